// Round 10
// baseline (234.102 us; speedup 1.0000x reference)
//
#include <hip/hip_runtime.h>
#include <hip/hip_cooperative_groups.h>

namespace cg = cooperative_groups;

#define IN_DIM 256
#define OUT_DIM 64
#define NEG_SLOPE 0.01f
#define CHUNK 1024   // edges per scatter chunk
#define KPT (CHUNK / 256)

typedef __attribute__((ext_vector_type(8))) short short8v;   // 8 bf16 (4 VGPRs)
typedef __attribute__((ext_vector_type(4))) float float4v;   // MFMA C/D

// fp32 -> bf16 round-to-nearest-even
__device__ __forceinline__ unsigned f2bf(float f) {
    unsigned u = __float_as_uint(f);
    return (u + 0x7FFFu + ((u >> 16) & 1u)) >> 16;
}
__device__ __forceinline__ float bf2f(unsigned short u) {
    return __uint_as_float((unsigned)u << 16);
}

// ---------------- K1: MFMA projection + fused el/er ------------------------
// One wave per 16-row tile, 4 x mfma_f32_16x16x32_bf16 (16 rows x 64 cols).
// C/D layout (HW-verified): col = lane&15, row = (lane>>4)*4 + reg.
// W is read fp32 and converted during the swizzled LDS staging (k_init gone).
__global__ __launch_bounds__(256, 3) void k1_mfma(
        const float* __restrict__ h, const float* __restrict__ W,
        const float* __restrict__ a,
        unsigned short* __restrict__ zb, float* __restrict__ el, float* __restrict__ er,
        int M) {
    __shared__ uint4 wlds[2048];          // 32 KB: W bf16, swizzled 16B slots

    // stage W (fp32, coalesced 32B/thread) -> convert -> swizzled LDS slots
    #pragma unroll
    for (int k = 0; k < 8; ++k) {
        int c = threadIdx.x + k * 256;    // slot id: row = c>>5, col-oct = c&31
        int row = c >> 5, col = c & 31;
        const float* wsrc = W + c * 8;
        float4 wa = *(const float4*)wsrc;
        float4 wb = *(const float4*)(wsrc + 4);
        uint4 pk;
        pk.x = f2bf(wa.x) | (f2bf(wa.y) << 16);
        pk.y = f2bf(wa.z) | (f2bf(wa.w) << 16);
        pk.z = f2bf(wb.x) | (f2bf(wb.y) << 16);
        pk.w = f2bf(wb.z) | (f2bf(wb.w) << 16);
        wlds[(row << 5) | (col ^ (row & 7))] = pk;
    }
    __syncthreads();

    const int lane = threadIdx.x & 63;
    const int wid  = (blockIdx.x * 256 + threadIdx.x) >> 6;
    const int r0 = wid * 16;
    if (r0 >= M) return;

    const int lrow = lane & 15;
    const int kgrp = lane >> 4;
    const int k0   = kgrp * 8;
    const int swz  = lrow & 7;

    const float* __restrict__ hrow = h + (size_t)(r0 + lrow) * IN_DIM;

    // burst-load the whole per-lane h strip (16 x dwordx4 in flight)
    float4 hreg[16];
    #pragma unroll
    for (int s = 0; s < 8; ++s) {
        hreg[2 * s]     = *(const float4*)(hrow + s * 32 + k0);
        hreg[2 * s + 1] = *(const float4*)(hrow + s * 32 + k0 + 4);
    }

    float4v acc[4];
    #pragma unroll
    for (int n = 0; n < 4; ++n) acc[n] = (float4v){0.f, 0.f, 0.f, 0.f};

    #pragma unroll
    for (int s = 0; s < 8; ++s) {
        float4 ha = hreg[2 * s], hb = hreg[2 * s + 1];
        short8v afrag;
        afrag[0] = (short)f2bf(ha.x); afrag[1] = (short)f2bf(ha.y);
        afrag[2] = (short)f2bf(ha.z); afrag[3] = (short)f2bf(ha.w);
        afrag[4] = (short)f2bf(hb.x); afrag[5] = (short)f2bf(hb.y);
        afrag[6] = (short)f2bf(hb.z); afrag[7] = (short)f2bf(hb.w);
        #pragma unroll
        for (int n = 0; n < 4; ++n) {
            const int slot = ((n * 16 + lrow) << 5) | ((s * 4 + kgrp) ^ swz);
            short8v bfrag = *(const short8v*)&wlds[slot];
            acc[n] = __builtin_amdgcn_mfma_f32_16x16x32_bf16(afrag, bfrag, acc[n], 0, 0, 0);
        }
    }

    float al4[4], ar4[4];
    #pragma unroll
    for (int n = 0; n < 4; ++n) {
        al4[n] = a[n * 16 + lrow];
        ar4[n] = a[OUT_DIM + n * 16 + lrow];
    }
    #pragma unroll
    for (int j = 0; j < 4; ++j) {
        const int row = r0 + kgrp * 4 + j;
        float vl = 0.f, vr = 0.f;
        #pragma unroll
        for (int n = 0; n < 4; ++n) {
            float v = acc[n][j];
            zb[(size_t)row * OUT_DIM + n * 16 + lrow] = (unsigned short)f2bf(v);
            vl += v * al4[n];
            vr += v * ar4[n];
        }
        #pragma unroll
        for (int m = 8; m >= 1; m >>= 1) {
            vl += __shfl_xor(vl, m, 64);
            vr += __shfl_xor(vr, m, 64);
        }
        if (lrow == 0) { el[row] = vl; er[row] = vr; }
    }
}

// ---------------- k_csr: cooperative count -> scatter -> build -------------
// P0: bucket histogram of dst (bucket = dst>>8).  grid.sync
// P1: partition edges into bucketbuf, coalesced runs.  grid.sync
// P2: per-bucket local CSR + inclusive ends.
// All loops grid-strided; no early returns (grid.sync participation).
__global__ __launch_bounds__(256) void k_csr(
        const int* __restrict__ src, const int* __restrict__ dst,
        int* __restrict__ bc, int* __restrict__ cursor,
        unsigned* __restrict__ bucketbuf,
        int* __restrict__ csr_src, int* __restrict__ ends,
        int N, int E, int nbuck, int nchunk) {
    __shared__ int bpre[256];                 // exclusive bucket starts
    __shared__ int t0[256], t1[256], t2[256], t3[256];
    __shared__ unsigned stag[CHUNK];
    cg::grid_group grid = cg::this_grid();
    const int t = threadIdx.x;
    const int grids = gridDim.x;

    // ---- P0: count ----
    t0[t] = 0;
    __syncthreads();
    for (int i = blockIdx.x * 256 + t; i < E; i += grids * 256)
        atomicAdd(&t0[dst[i] >> 8], 1);
    __syncthreads();
    if (t0[t]) atomicAdd(&bc[t], t0[t]);
    grid.sync();

    // ---- bucket-start scan (once per block; bc stable now) ----
    int bv = bc[t];                           // zeros beyond nbuck (memset)
    t0[t] = bv;
    __syncthreads();
    for (int off = 1; off < 256; off <<= 1) {
        int add = (t >= off) ? t0[t - off] : 0;
        __syncthreads();
        t0[t] += add;
        __syncthreads();
    }
    bpre[t] = t0[t] - bv;                     // exclusive
    __syncthreads();
    const int bstart_t = bpre[t];

    // ---- P1: scatter chunks ----
    for (int chunk = blockIdx.x; chunk < nchunk; chunk += grids) {
        const int base = chunk * CHUNK;
        const int n = min(CHUNK, E - base);

        t0[t] = 0;                            // cnt
        __syncthreads();
        int es[KPT], ed[KPT];
        #pragma unroll
        for (int k = 0; k < KPT; ++k) {
            int p = t + k * 256;
            if (p < n) {
                es[k] = src[base + p];
                ed[k] = dst[base + p];
                atomicAdd(&t0[ed[k] >> 8], 1);
            }
        }
        __syncthreads();
        t1[t] = t0[t];                        // scan -> exclusive lofs
        __syncthreads();
        for (int off = 1; off < 256; off <<= 1) {
            int add = (t >= off) ? t1[t - off] : 0;
            __syncthreads();
            t1[t] += add;
            __syncthreads();
        }
        t1[t] -= t0[t];
        __syncthreads();
        {
            int c = t0[t];
            int g = c ? atomicAdd(&cursor[t], c) : 0;
            t3[t] = bstart_t + g - t1[t];     // tb
        }
        t2[t] = t1[t];                        // lcur
        __syncthreads();
        #pragma unroll
        for (int k = 0; k < KPT; ++k) {
            int p = t + k * 256;
            if (p < n) {
                int b = ed[k] >> 8;
                int pos = atomicAdd(&t2[b], 1);
                stag[pos] = ((unsigned)ed[k] << 16) | (unsigned)es[k];
            }
        }
        __syncthreads();
        #pragma unroll
        for (int k = 0; k < KPT; ++k) {
            int p = t + k * 256;
            if (p < n) {
                unsigned v = stag[p];
                bucketbuf[t3[v >> 24] + p] = v;
            }
        }
        __syncthreads();
    }
    grid.sync();

    // ---- P2: build buckets ----
    for (int b = blockIdx.x; b < nbuck; b += grids) {
        const int start = bpre[b];
        const int cnt = bc[b];
        const int node0 = b << 8;
        const int nloc = min(256, N - node0);

        t0[t] = 0;                            // lcnt
        __syncthreads();
        for (int i = t; i < cnt; i += 256)
            atomicAdd(&t0[(bucketbuf[start + i] >> 16) & 255], 1);
        __syncthreads();
        t1[t] = t0[t];                        // inclusive scan
        __syncthreads();
        for (int off = 1; off < 256; off <<= 1) {
            int add = (t >= off) ? t1[t - off] : 0;
            __syncthreads();
            t1[t] += add;
            __syncthreads();
        }
        if (t < nloc) ends[node0 + t] = start + t1[t];
        t2[t] = t1[t] - t0[t];                // lcur (local exclusive)
        __syncthreads();
        for (int i = t; i < cnt; i += 256) {
            unsigned v = bucketbuf[start + i];
            int node = (v >> 16) & 255;
            int pos = atomicAdd(&t2[node], 1);
            csr_src[start + pos] = (int)(v & 0xFFFFu);
        }
        __syncthreads();
    }
}

// ---------------- K5: per-node softmax + gather-aggregate (no atomics) ------
// One wave per dst node. Paired-edge gather (lanes 0-31 even / 32-63 odd
// edges, uint loads = 2 bf16 cols); shfl_xor(32) folds halves; float2 stores.
__global__ __launch_bounds__(256) void k5_node(
        const int* __restrict__ csr_src, const int* __restrict__ ends,
        const float* __restrict__ el, const float* __restrict__ er,
        const unsigned short* __restrict__ zb, float* __restrict__ out, int N) {
    const int lane = threadIdx.x & 63;
    const int node = blockIdx.x * 4 + (threadIdx.x >> 6);
    if (node >= N) return;

    const int start = (node == 0) ? 0 : ends[node - 1];
    const int end   = ends[node];
    const int deg   = end - start;
    const int half  = lane >> 5;
    const int lh    = lane & 31;

    float rlo = 0.f, rhi = 0.f;

    if (deg > 0 && deg <= 64) {
        const float er_i = er[node];
        int   s0 = 0;
        float m  = -3.4e38f;
        float e0 = 0.0f;
        if (lane < deg) {
            s0 = csr_src[start + lane];
            float x = el[s0] + er_i;
            e0 = fmaxf(x, NEG_SLOPE * x);
            m  = e0;
        }
        #pragma unroll
        for (int msk = 32; msk; msk >>= 1) m = fmaxf(m, __shfl_xor(m, msk, 64));
        float ex0 = (lane < deg) ? __expf(e0 - m) : 0.0f;
        float sum = ex0;
        #pragma unroll
        for (int msk = 32; msk; msk >>= 1) sum += __shfl_xor(sum, msk, 64);
        const float inv = 1.0f / sum;

        const int npairs = (deg + 1) >> 1;
        float2 acc0 = {0.f, 0.f}, acc1 = {0.f, 0.f},
               acc2 = {0.f, 0.f}, acc3 = {0.f, 0.f};
        int p = 0;
        for (; p + 4 <= npairs; p += 4) {
            #pragma unroll
            for (int q = 0; q < 4; ++q) {
                int e  = 2 * (p + q) + half;
                int cl = (e < deg) ? e : (deg - 1);
                float wv = __shfl(ex0, cl, 64);
                int   sv = __shfl(s0,  cl, 64);
                if (e >= deg) wv = 0.0f;
                unsigned u = *(const unsigned*)(zb + (size_t)sv * OUT_DIM + lh * 2);
                float zl = bf2f((unsigned short)(u & 0xFFFFu));
                float zh = bf2f((unsigned short)(u >> 16));
                if (q == 0) { acc0.x += wv * zl; acc0.y += wv * zh; }
                else if (q == 1) { acc1.x += wv * zl; acc1.y += wv * zh; }
                else if (q == 2) { acc2.x += wv * zl; acc2.y += wv * zh; }
                else { acc3.x += wv * zl; acc3.y += wv * zh; }
            }
        }
        for (; p < npairs; ++p) {
            int e  = 2 * p + half;
            int cl = (e < deg) ? e : (deg - 1);
            float wv = __shfl(ex0, cl, 64);
            int   sv = __shfl(s0,  cl, 64);
            if (e >= deg) wv = 0.0f;
            unsigned u = *(const unsigned*)(zb + (size_t)sv * OUT_DIM + lh * 2);
            acc0.x += wv * bf2f((unsigned short)(u & 0xFFFFu));
            acc0.y += wv * bf2f((unsigned short)(u >> 16));
        }
        rlo = ((acc0.x + acc1.x) + (acc2.x + acc3.x));
        rhi = ((acc0.y + acc1.y) + (acc2.y + acc3.y));
        rlo += __shfl_xor(rlo, 32, 64);
        rhi += __shfl_xor(rhi, 32, 64);
        rlo *= inv; rhi *= inv;
    } else if (deg > 64) {
        const float er_i = er[node];
        float e0 = 0.0f, e1 = 0.0f;
        int   s0 = 0,    s1 = 0;
        float m = -3.4e38f;
        int t = 0;
        for (int j = start + lane; j < end; j += 64, ++t) {
            int s = csr_src[j];
            float x = el[s] + er_i;
            float e = fmaxf(x, NEG_SLOPE * x);
            if (t == 0) { e0 = e; s0 = s; }
            else if (t == 1) { e1 = e; s1 = s; }
            m = fmaxf(m, e);
        }
        #pragma unroll
        for (int msk = 32; msk; msk >>= 1) m = fmaxf(m, __shfl_xor(m, msk, 64));
        float sum = 0.0f;
        t = 0;
        for (int j = start + lane; j < end; j += 64, ++t) {
            float e;
            if (t == 0) e = e0;
            else if (t == 1) e = e1;
            else {
                int s = csr_src[j];
                float x = el[s] + er_i;
                e = fmaxf(x, NEG_SLOPE * x);
            }
            float ex = __expf(e - m);
            if (t == 0) e0 = ex; else if (t == 1) e1 = ex;
            sum += ex;
        }
        #pragma unroll
        for (int msk = 32; msk; msk >>= 1) sum += __shfl_xor(sum, msk, 64);
        const float inv = 1.0f / sum;

        float acc = 0.0f;
        for (int r = 0; r < deg; ++r) {
            int tt = r >> 6, owner = r & 63;
            int s; float ex;
            if (tt == 0)      { s = __shfl(s0, owner, 64); ex = __shfl(e0, owner, 64); }
            else if (tt == 1) { s = __shfl(s1, owner, 64); ex = __shfl(e1, owner, 64); }
            else {
                s = csr_src[start + r];
                float x = el[s] + er_i;
                float e = fmaxf(x, NEG_SLOPE * x);
                ex = __expf(e - m);
            }
            acc += ex * bf2f(zb[(size_t)s * OUT_DIM + lane]);
        }
        acc *= inv;
        rlo = __shfl(acc, 2 * lh, 64);
        rhi = __shfl(acc, 2 * lh + 1, 64);
    }

    if (lane < 32) {
        float2 o; o.x = rlo; o.y = rhi;
        *(float2*)(out + (size_t)node * OUT_DIM + lh * 2) = o;
    }
}

extern "C" void kernel_launch(void* const* d_in, const int* in_sizes, int n_in,
                              void* d_out, int out_size, void* d_ws, size_t ws_size,
                              hipStream_t stream) {
    const float* h   = (const float*)d_in[0];
    const float* W   = (const float*)d_in[1];
    const float* a   = (const float*)d_in[2];
    const int*   src = (const int*)d_in[3];
    const int*   dst = (const int*)d_in[4];
    float* out = (float*)d_out;

    const int N = in_sizes[0] / IN_DIM;     // 50000
    const int E = in_sizes[3];              // 800000
    const int nbuck = (N + 255) >> 8;       // 196
    const int nchunk = (E + CHUNK - 1) / CHUNK;  // 782

    // workspace layout (~13.4 MB)
    unsigned short* zb = (unsigned short*)d_ws;          // N*64 bf16 (6.4 MB)
    float* el   = (float*)(zb + (size_t)N * OUT_DIM);    // N
    float* er   = el + N;                                // N
    int*   ends = (int*)(er + N);                        // N (global inclusive ends)
    int*   csr_src = ends + N;                           // E
    unsigned* bucketbuf = (unsigned*)(csr_src + E);      // E
    int*   bc     = (int*)(bucketbuf + E);               // 256
    int*   cursor = bc + 256;                            // 256 (adjacent to bc)

    // zero bc + cursor (512 ints) — graph-capture-legal async memset
    hipMemsetAsync(bc, 0, 512 * sizeof(int), stream);

    {   // projection (W converted in-kernel now)
        const int waves = (N + 15) / 16;    // 3125 row-tiles
        k1_mfma<<<(waves + 3) / 4, 256, 0, stream>>>(h, W, a, zb, el, er, N);
    }

    {   // cooperative CSR build: count -> scatter -> build
        int occ = 0;
        if (hipOccupancyMaxActiveBlocksPerMultiprocessor(
                &occ, (const void*)k_csr, 256, 0) != hipSuccess || occ < 1)
            occ = 1;
        int grid = occ * 256;               // 256 CUs (MI355X)
        if (grid > nchunk) grid = nchunk;   // no more blocks than chunks
        int N_ = N, E_ = E, nb_ = nbuck, nc_ = nchunk;
        void* args[] = { (void*)&src, (void*)&dst, (void*)&bc, (void*)&cursor,
                         (void*)&bucketbuf, (void*)&csr_src, (void*)&ends,
                         (void*)&N_, (void*)&E_, (void*)&nb_, (void*)&nc_ };
        hipLaunchCooperativeKernel((const void*)k_csr, dim3(grid), dim3(256),
                                   args, 0, stream);
    }

    k5_node<<<(N + 3) / 4, 256, 0, stream>>>(csr_src, ends, el, er, zb, out, N);
}